// Round 3
// baseline (151.376 us; speedup 1.0000x reference)
//
#include <hip/hip_runtime.h>

#define NH    8
#define BROWS 32768
#define INF   16
#define CIN   32
#define OUTF  32
#define KTOT  544   // OUTF*(INF+1)

typedef __attribute__((ext_vector_type(8))) short short8;
typedef __attribute__((ext_vector_type(4))) float floatx4;

__device__ __forceinline__ short f2bf(float f) {
    __bf16 h = (__bf16)f;   // RNE f32->bf16
    return __builtin_bit_cast(short, h);
}

// Grid: (256, 8). Block: 256 threads = 4 waves.
// Wave w: pair = w>>1 (row-group), otile = w&1 (output half).
// Swapped MFMA: D[m=o][n=b] = W_i x cond^T; per-sample scale x1[b,i] applied
// to D (lane-local: D col = lane&15 = sample). Bias term = accumulator-init MFMA.
// No manual pipelining, no register arrays beyond wfrag (static-indexed) --
// keeps VGPRs ~130 < 168 cap, zero spill.
__global__ __launch_bounds__(256, 3) void meta_multilinear(
    const float* __restrict__ input,
    const float* __restrict__ cond,
    const float* __restrict__ weight,
    const float* __restrict__ bias,
    float* __restrict__ out)
{
    const int tid   = threadIdx.x;
    const int lane  = tid & 63;
    const int wave  = tid >> 6;     // 0..3
    const int pair  = wave >> 1;    // 0..1
    const int otile = wave & 1;     // 0..1
    const int r     = lane & 15;
    const int quad  = lane >> 4;    // 0..3
    const int c0    = quad * 8;     // K-slice start

    const int h = blockIdx.y;
    const int o = otile * 16 + r;   // this lane's A-row (output feature)

    const float* Wh = weight + (size_t)h * KTOT * CIN;
    const float* bh = bias   + (size_t)h * KTOT;

    // ---- register-resident A fragments: A[m=o][k=c] = W[h][o*17+i][c] ----
    short8 wfrag[17];
    #pragma unroll
    for (int i = 0; i < 17; ++i) {
        const float* src = Wh + (o * 17 + i) * CIN + c0;
        floatx4 w0 = *(const floatx4*)(src);
        floatx4 w1 = *(const floatx4*)(src + 4);
        short8 f;
        f[0]=f2bf(w0.x); f[1]=f2bf(w0.y); f[2]=f2bf(w0.z); f[3]=f2bf(w0.w);
        f[4]=f2bf(w1.x); f[5]=f2bf(w1.y); f[6]=f2bf(w1.z); f[7]=f2bf(w1.w);
        wfrag[i] = f;
    }

    // ---- bias A fragment: A[m=o][k=i] = bias[h][o*17+i], zero for i>=17 ----
    short8 bA;
    #pragma unroll
    for (int j = 0; j < 8; ++j) {
        const int i = c0 + j;
        short v = 0;
        if (i < 17) v = f2bf(bh[o * 17 + i]);   // exec-masked: no OOB load
        bA[j] = v;
    }

    const int pairId = blockIdx.x * 2 + pair;   // 0..511
    const int bbase  = pairId * 64;             // 4 tiles of 16 rows

    const float* condh = cond  + (size_t)h * BROWS * CIN;
    const float* inh   = input + (size_t)h * BROWS * INF;
    const floatx4 zero = {0.f, 0.f, 0.f, 0.f};

    #pragma unroll
    for (int it = 0; it < 4; ++it) {
        const int b0 = bbase + it * 16;

        // lane's cond slice: cond[h][b0+r][c0..c0+8)
        const float* crow = condh + (size_t)(b0 + r) * CIN + c0;
        floatx4 cA = *(const floatx4*)(crow);
        floatx4 cB = *(const floatx4*)(crow + 4);

        // lane's x1 row: input[h][b0+r][0..16)
        const float* xrow = inh + (size_t)(b0 + r) * INF;
        floatx4 x0 = *(const floatx4*)(xrow);
        floatx4 x1 = *(const floatx4*)(xrow + 4);
        floatx4 x2 = *(const floatx4*)(xrow + 8);
        floatx4 x3 = *(const floatx4*)(xrow + 12);

        // ---- cond -> bf16 B fragment: B[k=c][n=b], lane&15 = sample ----
        short8 cf;
        cf[0]=f2bf(cA.x); cf[1]=f2bf(cA.y); cf[2]=f2bf(cA.z); cf[3]=f2bf(cA.w);
        cf[4]=f2bf(cB.x); cf[5]=f2bf(cB.y); cf[6]=f2bf(cB.z); cf[7]=f2bf(cB.w);

        // ---- x1 as B fragment for bias term: B[k=i][n=b] = x1[b][i] ----
        short8 xb;
        if (quad == 0) {
            xb[0]=f2bf(x0.x); xb[1]=f2bf(x0.y); xb[2]=f2bf(x0.z); xb[3]=f2bf(x0.w);
            xb[4]=f2bf(x1.x); xb[5]=f2bf(x1.y); xb[6]=f2bf(x1.z); xb[7]=f2bf(x1.w);
        } else if (quad == 1) {
            xb[0]=f2bf(x2.x); xb[1]=f2bf(x2.y); xb[2]=f2bf(x2.z); xb[3]=f2bf(x2.w);
            xb[4]=f2bf(x3.x); xb[5]=f2bf(x3.y); xb[6]=f2bf(x3.z); xb[7]=f2bf(x3.w);
        } else if (quad == 2) {
            xb[0]=f2bf(1.0f); xb[1]=0; xb[2]=0; xb[3]=0;
            xb[4]=0; xb[5]=0; xb[6]=0; xb[7]=0;
        } else {
            xb[0]=0; xb[1]=0; xb[2]=0; xb[3]=0;
            xb[4]=0; xb[5]=0; xb[6]=0; xb[7]=0;
        }

        // ---- bias MFMA initializes accumulator 0; second acc breaks the chain ----
        floatx4 f0 = __builtin_amdgcn_mfma_f32_16x16x32_bf16(bA, xb, zero, 0, 0, 0);
        floatx4 f1 = zero;

        // ---- 17 independent MFMAs; D scaled by lane-local x1[b][i], f32 accum ----
        // All indices compile-time (rule #20: no runtime-indexed arrays).
        #define STEP(i, s) do { \
            floatx4 d_ = __builtin_amdgcn_mfma_f32_16x16x32_bf16(wfrag[(i)], cf, zero, 0, 0, 0); \
            if ((i) & 1) f1 += d_ * (s); else f0 += d_ * (s); \
        } while (0)
        STEP(0,  x0.x); STEP(1,  x0.y); STEP(2,  x0.z); STEP(3,  x0.w);
        STEP(4,  x1.x); STEP(5,  x1.y); STEP(6,  x1.z); STEP(7,  x1.w);
        STEP(8,  x2.x); STEP(9,  x2.y); STEP(10, x2.z); STEP(11, x2.w);
        STEP(12, x3.x); STEP(13, x3.y); STEP(14, x3.z); STEP(15, x3.w);
        STEP(16, 1.0f);
        #undef STEP

        const floatx4 facc = f0 + f1;

        // ---- store: lane writes 4 contiguous floats (row=b0+r, cols otile*16+quad*4..+4) ----
        float* dst = out + ((size_t)h * BROWS + b0 + r) * OUTF
                         + otile * 16 + quad * 4;
        *(floatx4*)dst = facc;
    }
}

extern "C" void kernel_launch(void* const* d_in, const int* in_sizes, int n_in,
                              void* d_out, int out_size, void* d_ws, size_t ws_size,
                              hipStream_t stream) {
    const float* input  = (const float*)d_in[0];
    const float* cond   = (const float*)d_in[1];
    const float* weight = (const float*)d_in[2];
    const float* bias   = (const float*)d_in[3];
    float* out = (float*)d_out;

    dim3 grid(256, NH, 1);
    dim3 block(256, 1, 1);
    hipLaunchKernelGGL(meta_multilinear, grid, block, 0, stream,
                       input, cond, weight, bias, out);
}

// Round 4
// 122.774 us; speedup vs baseline: 1.2330x; 1.2330x over previous
//
#include <hip/hip_runtime.h>

#define NH    8
#define BROWS 32768
#define INF   16
#define CIN   32
#define OUTF  32
#define KTOT  544   // OUTF*(INF+1)

#define XBLK   96                  // blocks per head -> 768 total (3/CU)
#define PAIRS  (XBLK * 2)          // wave-pairs per head = 192
#define TPAIRS (BROWS / 32)        // 32-row units per head = 1024

typedef __attribute__((ext_vector_type(8))) short short8;
typedef __attribute__((ext_vector_type(4))) float floatx4;

__device__ __forceinline__ short f2bf(float f) {
    __bf16 h = (__bf16)f;   // RNE f32->bf16
    return __builtin_bit_cast(short, h);
}

// Grid: (96, 8). Block: 256 threads = 4 waves = 2 pairs.
// Pair = {otile0, otile1} waves sharing 16-sample tiles; pairId in [0,192) per
// head grid-strides over 32-row units (2 tiles per iteration for ILP: all 12
// loads issued first, tile-B loads stay in flight during tile-A compute).
// Swapped MFMA: D[m=o][n=b] = W_i x cond^T, per-sample scale x1[b,i] applied
// to D (lane-local). Bias term = accumulator-init MFMA. Nontemporal stores.
__global__ __launch_bounds__(256, 3) void meta_multilinear(
    const float* __restrict__ input,
    const float* __restrict__ cond,
    const float* __restrict__ weight,
    const float* __restrict__ bias,
    float* __restrict__ out)
{
    const int tid   = threadIdx.x;
    const int lane  = tid & 63;
    const int wave  = tid >> 6;     // 0..3
    const int pair  = wave >> 1;    // 0..1
    const int otile = wave & 1;     // 0..1
    const int r     = lane & 15;
    const int quad  = lane >> 4;    // 0..3
    const int c0    = quad * 8;     // K-slice start

    const int h = blockIdx.y;
    const int o = otile * 16 + r;   // this lane's A-row (output feature)

    const float* Wh = weight + (size_t)h * KTOT * CIN;
    const float* bh = bias   + (size_t)h * KTOT;

    // ---- register-resident A fragments: A[m=o][k=c] = W[h][o*17+i][c] ----
    short8 wfrag[17];
    #pragma unroll
    for (int i = 0; i < 17; ++i) {
        const float* src = Wh + (o * 17 + i) * CIN + c0;
        floatx4 w0 = *(const floatx4*)(src);
        floatx4 w1 = *(const floatx4*)(src + 4);
        short8 f;
        f[0]=f2bf(w0.x); f[1]=f2bf(w0.y); f[2]=f2bf(w0.z); f[3]=f2bf(w0.w);
        f[4]=f2bf(w1.x); f[5]=f2bf(w1.y); f[6]=f2bf(w1.z); f[7]=f2bf(w1.w);
        wfrag[i] = f;
    }

    // ---- bias A fragment: A[m=o][k=i] = bias[h][o*17+i], zero for i>=17 ----
    short8 bA;
    #pragma unroll
    for (int j = 0; j < 8; ++j) {
        const int i = c0 + j;
        short v = 0;
        if (i < 17) v = f2bf(bh[o * 17 + i]);   // exec-masked: no OOB load
        bA[j] = v;
    }

    const int pairId = blockIdx.x * 2 + pair;   // 0..191 per head

    const float* condh = cond  + (size_t)h * BROWS * CIN;
    const float* inh   = input + (size_t)h * BROWS * INF;
    float*       outh  = out   + (size_t)h * BROWS * OUTF;
    const floatx4 zero = {0.f, 0.f, 0.f, 0.f};

    // one 16-row tile: build fragments, 18 MFMAs, scale-accumulate, store
    #define COMPUTE_TILE(cA, cB, x0, x1, x2, x3, brow) do {                          \
        short8 cf;                                                                   \
        cf[0]=f2bf(cA.x); cf[1]=f2bf(cA.y); cf[2]=f2bf(cA.z); cf[3]=f2bf(cA.w);      \
        cf[4]=f2bf(cB.x); cf[5]=f2bf(cB.y); cf[6]=f2bf(cB.z); cf[7]=f2bf(cB.w);      \
        short8 xb;                                                                   \
        if (quad == 0) {                                                             \
            xb[0]=f2bf(x0.x); xb[1]=f2bf(x0.y); xb[2]=f2bf(x0.z); xb[3]=f2bf(x0.w);  \
            xb[4]=f2bf(x1.x); xb[5]=f2bf(x1.y); xb[6]=f2bf(x1.z); xb[7]=f2bf(x1.w);  \
        } else if (quad == 1) {                                                      \
            xb[0]=f2bf(x2.x); xb[1]=f2bf(x2.y); xb[2]=f2bf(x2.z); xb[3]=f2bf(x2.w);  \
            xb[4]=f2bf(x3.x); xb[5]=f2bf(x3.y); xb[6]=f2bf(x3.z); xb[7]=f2bf(x3.w);  \
        } else if (quad == 2) {                                                      \
            xb[0]=f2bf(1.0f); xb[1]=0; xb[2]=0; xb[3]=0;                             \
            xb[4]=0; xb[5]=0; xb[6]=0; xb[7]=0;                                      \
        } else {                                                                     \
            xb[0]=0; xb[1]=0; xb[2]=0; xb[3]=0;                                      \
            xb[4]=0; xb[5]=0; xb[6]=0; xb[7]=0;                                      \
        }                                                                            \
        floatx4 f0 = __builtin_amdgcn_mfma_f32_16x16x32_bf16(bA, xb, zero, 0, 0, 0); \
        floatx4 f1 = zero;                                                           \
        STEP(0,  x0.x); STEP(1,  x0.y); STEP(2,  x0.z); STEP(3,  x0.w);              \
        STEP(4,  x1.x); STEP(5,  x1.y); STEP(6,  x1.z); STEP(7,  x1.w);              \
        STEP(8,  x2.x); STEP(9,  x2.y); STEP(10, x2.z); STEP(11, x2.w);              \
        STEP(12, x3.x); STEP(13, x3.y); STEP(14, x3.z); STEP(15, x3.w);              \
        STEP(16, 1.0f);                                                              \
        const floatx4 facc = f0 + f1;                                                \
        float* dst = outh + (size_t)((brow) + r) * OUTF + otile * 16 + quad * 4;     \
        __builtin_nontemporal_store(facc, (floatx4*)dst);                            \
    } while (0)

    #define STEP(i, s) do {                                                          \
        floatx4 d_ = __builtin_amdgcn_mfma_f32_16x16x32_bf16(wfrag[(i)], cf, zero, 0, 0, 0); \
        if ((i) & 1) f1 += d_ * (s); else f0 += d_ * (s);                            \
    } while (0)

    // grid-stride over 32-row units; 2 tiles per iteration, loads front-loaded
    for (int tp = pairId; tp < TPAIRS; tp += PAIRS) {
        const int bA0 = tp * 32;        // tile A rows [bA0, bA0+16)
        const int bB0 = bA0 + 16;       // tile B rows [bB0, bB0+16)

        // ---- issue ALL 12 loads (tile A then tile B) ----
        const float* crowA = condh + (size_t)(bA0 + r) * CIN + c0;
        floatx4 cAa = *(const floatx4*)(crowA);
        floatx4 cBa = *(const floatx4*)(crowA + 4);
        const float* xrowA = inh + (size_t)(bA0 + r) * INF;
        floatx4 x0a = *(const floatx4*)(xrowA);
        floatx4 x1a = *(const floatx4*)(xrowA + 4);
        floatx4 x2a = *(const floatx4*)(xrowA + 8);
        floatx4 x3a = *(const floatx4*)(xrowA + 12);

        const float* crowB = condh + (size_t)(bB0 + r) * CIN + c0;
        floatx4 cAb = *(const floatx4*)(crowB);
        floatx4 cBb = *(const floatx4*)(crowB + 4);
        const float* xrowB = inh + (size_t)(bB0 + r) * INF;
        floatx4 x0b = *(const floatx4*)(xrowB);
        floatx4 x1b = *(const floatx4*)(xrowB + 4);
        floatx4 x2b = *(const floatx4*)(xrowB + 8);
        floatx4 x3b = *(const floatx4*)(xrowB + 12);

        // ---- tile A compute (tile B loads remain in flight) ----
        COMPUTE_TILE(cAa, cBa, x0a, x1a, x2a, x3a, bA0);
        // ---- tile B compute ----
        COMPUTE_TILE(cAb, cBb, x0b, x1b, x2b, x3b, bB0);
    }

    #undef STEP
    #undef COMPUTE_TILE
}

extern "C" void kernel_launch(void* const* d_in, const int* in_sizes, int n_in,
                              void* d_out, int out_size, void* d_ws, size_t ws_size,
                              hipStream_t stream) {
    const float* input  = (const float*)d_in[0];
    const float* cond   = (const float*)d_in[1];
    const float* weight = (const float*)d_in[2];
    const float* bias   = (const float*)d_in[3];
    float* out = (float*)d_out;

    dim3 grid(XBLK, NH, 1);
    dim3 block(256, 1, 1);
    hipLaunchKernelGGL(meta_multilinear, grid, block, 0, stream,
                       input, cond, weight, bias, out);
}